// Round 1
// baseline (1382.445 us; speedup 1.0000x reference)
//
#include <hip/hip_runtime.h>
#include <math.h>

#define BQ 8
#define NPTS 16384
#define SQ 1024
#define KN 32
#define CIN 91
#define CINP 92
#define C 256
#define NQ (BQ * SQ)          // 8192 queries
#define PF_ELEMS (NQ * C)     // 2097152 floats of patch_feature

// ---------------------------------------------------------------------------
// Kernel A: ball query. One wave (64 lanes) per query. Scan points in index
// order; the reference's sort+slice == "first 32 indices within radius".
// Distance formula replicated EXACTLY (||c||^2+||p||^2-2c.p, fp32, no fma
// contraction) to avoid boundary-membership flips vs the numpy reference.
// ---------------------------------------------------------------------------
__global__ void ball_query_kernel(const float* __restrict__ xyz,
                                  const float* __restrict__ ctr,
                                  int* __restrict__ idx_ws,
                                  float* __restrict__ idx_out) {
    const int wid  = threadIdx.x >> 6;
    const int lane = threadIdx.x & 63;
    const int q = blockIdx.x * 4 + wid;   // 0..8191
    const int b = q >> 10;

    const float* xb = xyz + (size_t)b * NPTS * 3;
    const float cx = ctr[q * 3 + 0];
    const float cy = ctr[q * 3 + 1];
    const float cz = ctr[q * 3 + 2];
    // sum of squares, left-to-right, unfused
    const float sc = __fadd_rn(__fadd_rn(__fmul_rn(cx, cx), __fmul_rn(cy, cy)),
                               __fmul_rn(cz, cz));

    __shared__ int buf[4][KN];

    int count = 0;
    for (int base = 0; base < NPTS && count < KN; base += 64) {
        const int n = base + lane;
        const float px = xb[n * 3 + 0];
        const float py = xb[n * 3 + 1];
        const float pz = xb[n * 3 + 2];
        const float sp = __fadd_rn(__fadd_rn(__fmul_rn(px, px), __fmul_rn(py, py)),
                                   __fmul_rn(pz, pz));
        const float dt = __fadd_rn(__fadd_rn(__fmul_rn(cx, px), __fmul_rn(cy, py)),
                                   __fmul_rn(cz, pz));
        const float sqr = __fsub_rn(__fadd_rn(sc, sp), __fmul_rn(2.0f, dt));
        const bool inball = (sqr <= 0.0625f);   // !(sqr > r^2)

        const unsigned long long m = __ballot(inball);
        const int prefix = __popcll(m & ((1ull << lane) - 1ull));
        const int pos = count + prefix;
        if (inball && pos < KN) buf[wid][pos] = n;
        count += (int)__popcll(m);
    }
    if (count > KN) count = KN;

    __syncthreads();   // make buf writes visible across lanes/waves

    const int first = (count > 0) ? buf[wid][0] : NPTS;
    if (lane < KN) {
        const int v = (lane < count) ? buf[wid][lane] : first;
        idx_ws[q * KN + lane]  = v;
        idx_out[q * KN + lane] = (float)v;
    }
}

// ---------------------------------------------------------------------------
// Kernel B: gather + posenc + MLP1(+LN+GeLU) + MLP2(+LN) + max over K.
// One block (128 threads) per query; each thread owns channels t and t+128.
// ---------------------------------------------------------------------------
__device__ __forceinline__ float gelu_exact(float x) {
    return 0.5f * x * (1.0f + erff(x * 0.70710678118654752440f));
}

__global__ void __launch_bounds__(128)
encoder_kernel(const float* __restrict__ xyz,
               const float* __restrict__ pf,
               const float* __restrict__ ctr,
               const float* __restrict__ W1, const float* __restrict__ b1,
               const float* __restrict__ g1, const float* __restrict__ be1,
               const float* __restrict__ W2, const float* __restrict__ b2,
               const float* __restrict__ g2, const float* __restrict__ be2,
               const int* __restrict__ idx_ws,
               float* __restrict__ out) {
    const int q = blockIdx.x;           // 0..8191
    const int b = q >> 10;
    const int t = threadIdx.x;          // 0..127
    const int wid  = t >> 6;
    const int lane = t & 63;
    const int o0 = t;
    const int o1 = t + 128;

    __shared__ __align__(16) float Xs[KN][CINP];   // 92 cols, col 91 zero pad
    __shared__ __align__(16) float H[KN][C];

    const float cx = ctr[q * 3 + 0];
    const float cy = ctr[q * 3 + 1];
    const float cz = ctr[q * 3 + 2];
    const float* xb  = xyz + (size_t)b * NPTS * 3;

    // ---- Phase 1: build grouped input X[k][0..91] ----
    {
        const int tc = t & 3;           // 4 threads per row
        const int k  = t >> 2;          // 0..31
        int n = idx_ws[q * KN + k];
        if (n > NPTS - 1) n = NPTS - 1; // JAX OOB gather clamps
        const float rx = xb[n * 3 + 0] - cx;
        const float ry = xb[n * 3 + 1] - cy;
        const float rz = xb[n * 3 + 2] - cz;
        const float* pfr = pf + ((size_t)b * NPTS + n) * 64;
        const int c0 = tc * 23;
        #pragma unroll
        for (int j = 0; j < 23; ++j) {
            const int c = c0 + j;
            float v;
            if (c < 64) {
                v = pfr[c];
            } else if (c < 67) {
                v = (c == 64) ? rx : ((c == 65) ? ry : rz);
            } else if (c < 91) {
                const int jj = c - 67;
                const int d = jj >> 3;
                const int m = jj & 7;
                const float f = (float)(1 << (m & 3));
                const float r = (d == 0) ? rx : ((d == 1) ? ry : rz);
                v = (m < 4) ? sinf(r * f) : cosf(r * f);
            } else {
                v = 0.0f;               // pad col 91
            }
            Xs[k][c] = v;
        }
    }
    __syncthreads();

    // ---- Phase 2: layer 1 matmul (X[32][91] @ W1[91][256]) ----
    float acc0[KN], acc1[KN];
    #pragma unroll
    for (int k = 0; k < KN; ++k) { acc0[k] = 0.0f; acc1[k] = 0.0f; }

    for (int i4 = 0; i4 < 23; ++i4) {
        const int i = i4 * 4;
        const float w00 = W1[(i + 0) * C + o0];
        const float w01 = W1[(i + 1) * C + o0];
        const float w02 = W1[(i + 2) * C + o0];
        const float w03 = (i + 3 < CIN) ? W1[(i + 3) * C + o0] : 0.0f;
        const float w10 = W1[(i + 0) * C + o1];
        const float w11 = W1[(i + 1) * C + o1];
        const float w12 = W1[(i + 2) * C + o1];
        const float w13 = (i + 3 < CIN) ? W1[(i + 3) * C + o1] : 0.0f;
        #pragma unroll
        for (int k = 0; k < KN; ++k) {
            const float4 xv = *(const float4*)(&Xs[k][i]);
            acc0[k] = fmaf(xv.w, w03, fmaf(xv.z, w02, fmaf(xv.y, w01, fmaf(xv.x, w00, acc0[k]))));
            acc1[k] = fmaf(xv.w, w13, fmaf(xv.z, w12, fmaf(xv.y, w11, fmaf(xv.x, w10, acc1[k]))));
        }
    }

    // store raw h1 (+bias)
    {
        const float bb0 = b1[o0], bb1 = b1[o1];
        #pragma unroll
        for (int k = 0; k < KN; ++k) {
            H[k][o0] = acc0[k] + bb0;
            H[k][o1] = acc1[k] + bb1;
        }
    }
    __syncthreads();

    // ---- Phase 3: LN + GeLU in place on H ----
    {
        const float ga = g1[lane], gb = g1[lane + 64], gc = g1[lane + 128], gd = g1[lane + 192];
        const float ba = be1[lane], bbt = be1[lane + 64], bc = be1[lane + 128], bd = be1[lane + 192];
        for (int k = wid; k < KN; k += 2) {
            float v0 = H[k][lane], v1 = H[k][lane + 64], v2 = H[k][lane + 128], v3 = H[k][lane + 192];
            float s  = (v0 + v1) + (v2 + v3);
            float s2 = (v0 * v0 + v1 * v1) + (v2 * v2 + v3 * v3);
            #pragma unroll
            for (int off = 1; off < 64; off <<= 1) {
                s  += __shfl_xor(s, off, 64);
                s2 += __shfl_xor(s2, off, 64);
            }
            const float mu  = s * (1.0f / 256.0f);
            const float var = s2 * (1.0f / 256.0f) - mu * mu;
            const float rs  = 1.0f / sqrtf(var + 1e-5f);
            v0 = gelu_exact((v0 - mu) * rs * ga + ba);
            v1 = gelu_exact((v1 - mu) * rs * gb + bbt);
            v2 = gelu_exact((v2 - mu) * rs * gc + bc);
            v3 = gelu_exact((v3 - mu) * rs * gd + bd);
            H[k][lane] = v0; H[k][lane + 64] = v1; H[k][lane + 128] = v2; H[k][lane + 192] = v3;
        }
    }
    __syncthreads();

    // ---- Phase 4: layer 2 matmul (H[32][256] @ W2[256][256]) ----
    #pragma unroll
    for (int k = 0; k < KN; ++k) { acc0[k] = 0.0f; acc1[k] = 0.0f; }

    for (int i4 = 0; i4 < 64; ++i4) {
        const int i = i4 * 4;
        const float w00 = W2[(i + 0) * C + o0];
        const float w01 = W2[(i + 1) * C + o0];
        const float w02 = W2[(i + 2) * C + o0];
        const float w03 = W2[(i + 3) * C + o0];
        const float w10 = W2[(i + 0) * C + o1];
        const float w11 = W2[(i + 1) * C + o1];
        const float w12 = W2[(i + 2) * C + o1];
        const float w13 = W2[(i + 3) * C + o1];
        #pragma unroll
        for (int k = 0; k < KN; ++k) {
            const float4 xv = *(const float4*)(&H[k][i]);
            acc0[k] = fmaf(xv.w, w03, fmaf(xv.z, w02, fmaf(xv.y, w01, fmaf(xv.x, w00, acc0[k]))));
            acc1[k] = fmaf(xv.w, w13, fmaf(xv.z, w12, fmaf(xv.y, w11, fmaf(xv.x, w10, acc1[k]))));
        }
    }
    __syncthreads();   // everyone done READING H before overwrite

    {
        const float bb0 = b2[o0], bb1 = b2[o1];
        #pragma unroll
        for (int k = 0; k < KN; ++k) {
            H[k][o0] = acc0[k] + bb0;
            H[k][o1] = acc1[k] + bb1;
        }
    }
    __syncthreads();

    // ---- Phase 5: LN (no activation) ----
    {
        const float ga = g2[lane], gb = g2[lane + 64], gc = g2[lane + 128], gd = g2[lane + 192];
        const float ba = be2[lane], bbt = be2[lane + 64], bc = be2[lane + 128], bd = be2[lane + 192];
        for (int k = wid; k < KN; k += 2) {
            float v0 = H[k][lane], v1 = H[k][lane + 64], v2 = H[k][lane + 128], v3 = H[k][lane + 192];
            float s  = (v0 + v1) + (v2 + v3);
            float s2 = (v0 * v0 + v1 * v1) + (v2 * v2 + v3 * v3);
            #pragma unroll
            for (int off = 1; off < 64; off <<= 1) {
                s  += __shfl_xor(s, off, 64);
                s2 += __shfl_xor(s2, off, 64);
            }
            const float mu  = s * (1.0f / 256.0f);
            const float var = s2 * (1.0f / 256.0f) - mu * mu;
            const float rs  = 1.0f / sqrtf(var + 1e-5f);
            H[k][lane]       = (v0 - mu) * rs * ga + ba;
            H[k][lane + 64]  = (v1 - mu) * rs * gb + bbt;
            H[k][lane + 128] = (v2 - mu) * rs * gc + bc;
            H[k][lane + 192] = (v3 - mu) * rs * gd + bd;
        }
    }
    __syncthreads();

    // ---- Phase 6: max over K, write out ----
    float m0 = -INFINITY, m1 = -INFINITY;
    #pragma unroll
    for (int k = 0; k < KN; ++k) {
        m0 = fmaxf(m0, H[k][o0]);
        m1 = fmaxf(m1, H[k][o1]);
    }
    out[(size_t)q * C + o0] = m0;
    out[(size_t)q * C + o1] = m1;
}

extern "C" void kernel_launch(void* const* d_in, const int* in_sizes, int n_in,
                              void* d_out, int out_size, void* d_ws, size_t ws_size,
                              hipStream_t stream) {
    const float* xyz = (const float*)d_in[0];
    const float* pf  = (const float*)d_in[1];
    const float* ctr = (const float*)d_in[2];
    const float* W1  = (const float*)d_in[3];
    const float* b1  = (const float*)d_in[4];
    const float* g1  = (const float*)d_in[5];
    const float* be1 = (const float*)d_in[6];
    const float* W2  = (const float*)d_in[7];
    const float* b2  = (const float*)d_in[8];
    const float* g2  = (const float*)d_in[9];
    const float* be2 = (const float*)d_in[10];

    float* out = (float*)d_out;
    int* idx_ws = (int*)d_ws;

    ball_query_kernel<<<NQ / 4, 256, 0, stream>>>(xyz, ctr, idx_ws, out + PF_ELEMS);
    encoder_kernel<<<NQ, 128, 0, stream>>>(xyz, pf, ctr,
                                           W1, b1, g1, be1,
                                           W2, b2, g2, be2,
                                           idx_ws, out);
}

// Round 2
// 294.816 us; speedup vs baseline: 4.6892x; 4.6892x over previous
//
#include <hip/hip_runtime.h>
#include <math.h>

#define BQ 8
#define NPTS 16384
#define SQ 1024
#define KN 32
#define C 256
#define NQ (BQ * SQ)          // 8192 queries
#define PF_ELEMS (NQ * C)

// ws layout (bytes): [0, 512K) u16 idx; then f16 W1 packed; then f16 W2 packed
#define IDX_WS_BYTES (NQ * KN * 2)                  // 524288
#define W1P_OFF_ELEM 0                              // within w-pack region
#define W1P_ELEMS (3 * 16 * 64 * 8)                 // 24576  (Ktiles=3, Ntiles=16)
#define W2P_ELEMS (8 * 16 * 64 * 8)                 // 65536  (Ktiles=8)

typedef _Float16 half8 __attribute__((ext_vector_type(8)));
typedef _Float16 half4v __attribute__((ext_vector_type(4)));
typedef float f32x4 __attribute__((ext_vector_type(4)));

// ---------------------------------------------------------------------------
// Kernel A: ball query (unchanged logic; u16 idx to ws). One wave per query.
// Reference's sort+slice == first 32 indices within radius. Distance formula
// replicated exactly (fp32, unfused) to avoid boundary flips vs numpy.
// ---------------------------------------------------------------------------
__global__ void ball_query_kernel(const float* __restrict__ xyz,
                                  const float* __restrict__ ctr,
                                  unsigned short* __restrict__ idx_ws,
                                  float* __restrict__ idx_out) {
    const int wid  = threadIdx.x >> 6;
    const int lane = threadIdx.x & 63;
    const int q = blockIdx.x * 4 + wid;
    const int b = q >> 10;

    const float* xb = xyz + (size_t)b * NPTS * 3;
    const float cx = ctr[q * 3 + 0];
    const float cy = ctr[q * 3 + 1];
    const float cz = ctr[q * 3 + 2];
    const float sc = __fadd_rn(__fadd_rn(__fmul_rn(cx, cx), __fmul_rn(cy, cy)),
                               __fmul_rn(cz, cz));

    __shared__ int buf[4][KN];

    int count = 0;
    for (int base = 0; base < NPTS && count < KN; base += 64) {
        const int n = base + lane;
        const float px = xb[n * 3 + 0];
        const float py = xb[n * 3 + 1];
        const float pz = xb[n * 3 + 2];
        const float sp = __fadd_rn(__fadd_rn(__fmul_rn(px, px), __fmul_rn(py, py)),
                                   __fmul_rn(pz, pz));
        const float dt = __fadd_rn(__fadd_rn(__fmul_rn(cx, px), __fmul_rn(cy, py)),
                                   __fmul_rn(cz, pz));
        const float sqr = __fsub_rn(__fadd_rn(sc, sp), __fmul_rn(2.0f, dt));
        const bool inball = (sqr <= 0.0625f);

        const unsigned long long m = __ballot(inball);
        const int prefix = __popcll(m & ((1ull << lane) - 1ull));
        const int pos = count + prefix;
        if (inball && pos < KN) buf[wid][pos] = n;
        count += (int)__popcll(m);
    }
    if (count > KN) count = KN;

    __syncthreads();

    const int first = (count > 0) ? buf[wid][0] : NPTS;
    if (lane < KN) {
        const int v = (lane < count) ? buf[wid][lane] : first;
        idx_ws[q * KN + lane]  = (unsigned short)v;
        idx_out[q * KN + lane] = (float)v;
    }
}

// ---------------------------------------------------------------------------
// Prep: pack W1 (91x256, K-padded to 96) and W2 (256x256) into f16
// B-fragment order for mfma_f32_16x16x32_f16:
//   lane holds B[k = ktile*32 + (lane>>4)*8 + j][n = ntile*16 + (lane&15)], j=0..7
//   flat = ((ktile*16 + ntile)*64 + lane)*8 + j
// ---------------------------------------------------------------------------
__global__ void prep_w_kernel(const float* __restrict__ W1,
                              const float* __restrict__ W2,
                              _Float16* __restrict__ wp) {
    const int e = blockIdx.x * 256 + threadIdx.x;  // 0 .. 90111
    if (e < W1P_ELEMS) {
        const int j = e & 7, lane = (e >> 3) & 63, nt = (e >> 9) & 15, kt = e >> 13;
        const int k = kt * 32 + (lane >> 4) * 8 + j;
        const int n = nt * 16 + (lane & 15);
        wp[e] = (_Float16)((k < 91) ? W1[k * C + n] : 0.0f);
    } else {
        const int e2 = e - W1P_ELEMS;
        const int j = e2 & 7, lane = (e2 >> 3) & 63, nt = (e2 >> 9) & 15, kt = e2 >> 13;
        const int k = kt * 32 + (lane >> 4) * 8 + j;
        const int n = nt * 16 + (lane & 15);
        wp[e] = (_Float16)W2[k * C + n];
    }
}

__device__ __forceinline__ float gelu_exact(float x) {
    return 0.5f * x * (1.0f + erff(x * 0.70710678118654752440f));
}

// ---------------------------------------------------------------------------
// Kernel B: one query per 256-thread block (4 waves). MFMA f16 GEMMs,
// fp32 LN/GeLU/max. Wave w owns output channels [w*64, w*64+64).
// ---------------------------------------------------------------------------
__global__ void __launch_bounds__(256, 3)
encoder_mfma(const float* __restrict__ xyz,
             const float* __restrict__ pf,
             const float* __restrict__ ctr,
             const float* __restrict__ b1, const float* __restrict__ g1,
             const float* __restrict__ be1,
             const float* __restrict__ b2, const float* __restrict__ g2,
             const float* __restrict__ be2,
             const unsigned short* __restrict__ idx_ws,
             const _Float16* __restrict__ w1p,
             const _Float16* __restrict__ w2p,
             float* __restrict__ out) {
    const int q = blockIdx.x;
    const int b = q >> 10;
    const int t = threadIdx.x;
    const int w = t >> 6;
    const int lane = t & 63;
    const int quad = lane >> 4;
    const int l15  = lane & 15;

    // H32 stride 260: C-frag stores land 2-way max (free). 33280 B.
    __shared__ float H32[KN][260];
    // Region2 (16896 B) time-shares: Xs f16[32][104] -> Hf f16[32][264] -> Pmax f32[4][256]
    __shared__ __align__(16) unsigned char R2[KN * 264 * 2];
    _Float16 (*Xs)[104]  = reinterpret_cast<_Float16(*)[104]>(R2);
    _Float16 (*Hf)[264]  = reinterpret_cast<_Float16(*)[264]>(R2);
    float    (*Pmax)[256] = reinterpret_cast<float(*)[256]>(R2);

    // ---- Phase 1: gather + rel + posenc into Xs (f16, K-padded to 96) ----
    {
        const int k  = t >> 3;          // neighbor row 0..31
        const int tc = t & 7;           // 8 threads per row
        int n = idx_ws[q * KN + k];
        if (n > NPTS - 1) n = NPTS - 1; // JAX OOB gather clamp
        const float cx = ctr[q * 3 + 0];
        const float cy = ctr[q * 3 + 1];
        const float cz = ctr[q * 3 + 2];
        const float* xb  = xyz + (size_t)b * NPTS * 3;
        const float* pfr = pf + ((size_t)b * NPTS + n) * 64;

        // 8 consecutive feature channels
        const float4 f0 = *(const float4*)(pfr + tc * 8);
        const float4 f1 = *(const float4*)(pfr + tc * 8 + 4);
        half8 hv;
        hv[0] = (_Float16)f0.x; hv[1] = (_Float16)f0.y;
        hv[2] = (_Float16)f0.z; hv[3] = (_Float16)f0.w;
        hv[4] = (_Float16)f1.x; hv[5] = (_Float16)f1.y;
        hv[6] = (_Float16)f1.z; hv[7] = (_Float16)f1.w;
        *(half8*)&Xs[k][tc * 8] = hv;

        // 4 misc channels at c = 64 + tc*4  (rel, posenc, zero-pad to 96)
        const float rx = xb[n * 3 + 0] - cx;
        const float ry = xb[n * 3 + 1] - cy;
        const float rz = xb[n * 3 + 2] - cz;
        half4v ov;
        #pragma unroll
        for (int j = 0; j < 4; ++j) {
            const int c = 64 + tc * 4 + j;
            float v;
            if (c < 67) {
                v = (c == 64) ? rx : ((c == 65) ? ry : rz);
            } else if (c < 91) {
                const int jj = c - 67;
                const int d = jj >> 3;
                const int m = jj & 7;
                const float f = (float)(1 << (m & 3));
                const float r = (d == 0) ? rx : ((d == 1) ? ry : rz);
                v = (m < 4) ? sinf(r * f) : cosf(r * f);
            } else {
                v = 0.0f;
            }
            ov[j] = (_Float16)v;
        }
        *(half4v*)&Xs[k][64 + tc * 4] = ov;
    }
    __syncthreads();

    // ---- Phase 2: GEMM1  X[32x96] @ W1[96x256] -> H32 (+b1) ----
    {
        f32x4 acc[2][4];
        #pragma unroll
        for (int mt = 0; mt < 2; ++mt)
            #pragma unroll
            for (int nt = 0; nt < 4; ++nt)
                acc[mt][nt] = (f32x4){0.f, 0.f, 0.f, 0.f};

        #pragma unroll
        for (int kt = 0; kt < 3; ++kt) {
            const half8 a0 = *(const half8*)&Xs[l15][kt * 32 + quad * 8];
            const half8 a1 = *(const half8*)&Xs[16 + l15][kt * 32 + quad * 8];
            #pragma unroll
            for (int nt = 0; nt < 4; ++nt) {
                const int ntg = w * 4 + nt;
                const half8 bf = *(const half8*)&w1p[((kt * 16 + ntg) * 64 + lane) * 8];
                acc[0][nt] = __builtin_amdgcn_mfma_f32_16x16x32_f16(a0, bf, acc[0][nt], 0, 0, 0);
                acc[1][nt] = __builtin_amdgcn_mfma_f32_16x16x32_f16(a1, bf, acc[1][nt], 0, 0, 0);
            }
        }
        #pragma unroll
        for (int nt = 0; nt < 4; ++nt) {
            const int col = w * 64 + nt * 16 + l15;
            const float bb = b1[col];
            #pragma unroll
            for (int mt = 0; mt < 2; ++mt)
                #pragma unroll
                for (int r = 0; r < 4; ++r)
                    H32[mt * 16 + quad * 4 + r][col] = acc[mt][nt][r] + bb;
        }
    }
    __syncthreads();

    // ---- Phase 3: LN + GeLU (fp32 stats) -> Hf (f16). Wave w: rows w*8..w*8+7,
    //      lane: channels 4*lane..4*lane+3 ----
    {
        const float4 gv = *(const float4*)&g1[4 * lane];
        const float4 bv = *(const float4*)&be1[4 * lane];
        #pragma unroll
        for (int i = 0; i < 8; ++i) {
            const int k = w * 8 + i;
            const float4 v = *(const float4*)&H32[k][4 * lane];
            float s  = (v.x + v.y) + (v.z + v.w);
            float s2 = (v.x * v.x + v.y * v.y) + (v.z * v.z + v.w * v.w);
            #pragma unroll
            for (int off = 1; off < 64; off <<= 1) {
                s  += __shfl_xor(s, off, 64);
                s2 += __shfl_xor(s2, off, 64);
            }
            const float mu  = s * (1.0f / 256.0f);
            const float var = s2 * (1.0f / 256.0f) - mu * mu;
            const float rs  = 1.0f / sqrtf(var + 1e-5f);
            half4v h;
            h[0] = (_Float16)gelu_exact((v.x - mu) * rs * gv.x + bv.x);
            h[1] = (_Float16)gelu_exact((v.y - mu) * rs * gv.y + bv.y);
            h[2] = (_Float16)gelu_exact((v.z - mu) * rs * gv.z + bv.z);
            h[3] = (_Float16)gelu_exact((v.w - mu) * rs * gv.w + bv.w);
            *(half4v*)&Hf[k][4 * lane] = h;
        }
    }
    __syncthreads();

    // ---- Phase 4: GEMM2  H[32x256] @ W2[256x256] -> H32 (+b2) ----
    {
        f32x4 acc[2][4];
        #pragma unroll
        for (int mt = 0; mt < 2; ++mt)
            #pragma unroll
            for (int nt = 0; nt < 4; ++nt)
                acc[mt][nt] = (f32x4){0.f, 0.f, 0.f, 0.f};

        #pragma unroll
        for (int kt = 0; kt < 8; ++kt) {
            const half8 a0 = *(const half8*)&Hf[l15][kt * 32 + quad * 8];
            const half8 a1 = *(const half8*)&Hf[16 + l15][kt * 32 + quad * 8];
            #pragma unroll
            for (int nt = 0; nt < 4; ++nt) {
                const int ntg = w * 4 + nt;
                const half8 bf = *(const half8*)&w2p[((kt * 16 + ntg) * 64 + lane) * 8];
                acc[0][nt] = __builtin_amdgcn_mfma_f32_16x16x32_f16(a0, bf, acc[0][nt], 0, 0, 0);
                acc[1][nt] = __builtin_amdgcn_mfma_f32_16x16x32_f16(a1, bf, acc[1][nt], 0, 0, 0);
            }
        }
        __syncthreads();   // all Hf / H32 reads done before overwrite below? (Hf reads above; H32 writes next)
        #pragma unroll
        for (int nt = 0; nt < 4; ++nt) {
            const int col = w * 64 + nt * 16 + l15;
            const float bb = b2[col];
            #pragma unroll
            for (int mt = 0; mt < 2; ++mt)
                #pragma unroll
                for (int r = 0; r < 4; ++r)
                    H32[mt * 16 + quad * 4 + r][col] = acc[mt][nt][r] + bb;
        }
    }
    __syncthreads();

    // ---- Phase 5: LN (no act) + per-wave partial max over its 8 rows ----
    {
        const float4 gv = *(const float4*)&g2[4 * lane];
        const float4 bv = *(const float4*)&be2[4 * lane];
        float m0 = -INFINITY, m1 = -INFINITY, m2 = -INFINITY, m3 = -INFINITY;
        #pragma unroll
        for (int i = 0; i < 8; ++i) {
            const int k = w * 8 + i;
            const float4 v = *(const float4*)&H32[k][4 * lane];
            float s  = (v.x + v.y) + (v.z + v.w);
            float s2 = (v.x * v.x + v.y * v.y) + (v.z * v.z + v.w * v.w);
            #pragma unroll
            for (int off = 1; off < 64; off <<= 1) {
                s  += __shfl_xor(s, off, 64);
                s2 += __shfl_xor(s2, off, 64);
            }
            const float mu  = s * (1.0f / 256.0f);
            const float var = s2 * (1.0f / 256.0f) - mu * mu;
            const float rs  = 1.0f / sqrtf(var + 1e-5f);
            m0 = fmaxf(m0, (v.x - mu) * rs * gv.x + bv.x);
            m1 = fmaxf(m1, (v.y - mu) * rs * gv.y + bv.y);
            m2 = fmaxf(m2, (v.z - mu) * rs * gv.z + bv.z);
            m3 = fmaxf(m3, (v.w - mu) * rs * gv.w + bv.w);
        }
        float4 vm; vm.x = m0; vm.y = m1; vm.z = m2; vm.w = m3;
        *(float4*)&Pmax[w][4 * lane] = vm;   // R2 reuse: Hf dead since phase-4 sync
    }
    __syncthreads();

    // ---- Phase 6: combine 4 partial maxes, write out ----
    {
        const float m = fmaxf(fmaxf(Pmax[0][t], Pmax[1][t]),
                              fmaxf(Pmax[2][t], Pmax[3][t]));
        out[(size_t)q * C + t] = m;
    }
}

extern "C" void kernel_launch(void* const* d_in, const int* in_sizes, int n_in,
                              void* d_out, int out_size, void* d_ws, size_t ws_size,
                              hipStream_t stream) {
    const float* xyz = (const float*)d_in[0];
    const float* pf  = (const float*)d_in[1];
    const float* ctr = (const float*)d_in[2];
    const float* W1  = (const float*)d_in[3];
    const float* b1  = (const float*)d_in[4];
    const float* g1  = (const float*)d_in[5];
    const float* be1 = (const float*)d_in[6];
    const float* W2  = (const float*)d_in[7];
    const float* b2  = (const float*)d_in[8];
    const float* g2  = (const float*)d_in[9];
    const float* be2 = (const float*)d_in[10];

    float* out = (float*)d_out;
    unsigned short* idx_ws = (unsigned short*)d_ws;
    _Float16* wp = (_Float16*)((char*)d_ws + IDX_WS_BYTES);

    prep_w_kernel<<<(W1P_ELEMS + W2P_ELEMS) / 256, 256, 0, stream>>>(W1, W2, wp);
    ball_query_kernel<<<NQ / 4, 256, 0, stream>>>(xyz, ctr, idx_ws, out + PF_ELEMS);
    encoder_mfma<<<NQ, 256, 0, stream>>>(xyz, pf, ctr,
                                         b1, g1, be1, b2, g2, be2,
                                         idx_ws, wp, wp + W1P_ELEMS, out);
}